// Round 1
// baseline (53.141 us; speedup 1.0000x reference)
//
#include <hip/hip_runtime.h>

#define TPB 256
#define RB 4   // rows per thread in pair kernel

// Kernel 1: X = XX @ W1^T + b1 (raw, pre-standardize), + block partial sum/sumsq
__global__ __launch_bounds__(TPB) void trial_kernel(
    const float2* __restrict__ XX, const float* __restrict__ W1,
    const float* __restrict__ b1, float4* __restrict__ packed,
    float* __restrict__ stats, int nblocks)
{
    int tid = threadIdx.x;
    int i = blockIdx.x * TPB + tid;
    float2 x = XX[i];
    float w00 = W1[0], w01 = W1[1], w10 = W1[2], w11 = W1[3];
    float y0 = fmaf(x.y, w01, fmaf(x.x, w00, b1[0]));
    float y1 = fmaf(x.y, w11, fmaf(x.x, w10, b1[1]));
    packed[i] = make_float4(y0, y1, 0.f, 0.f);

    float s = y0 + y1;
    float q = fmaf(y0, y0, y1 * y1);
#pragma unroll
    for (int off = 32; off > 0; off >>= 1) {
        s += __shfl_xor(s, off, 64);
        q += __shfl_xor(q, off, 64);
    }
    __shared__ float ls[TPB / 64], lq[TPB / 64];
    int wave = tid >> 6, lane = tid & 63;
    if (lane == 0) { ls[wave] = s; lq[wave] = q; }
    __syncthreads();
    if (tid == 0) {
        float S = 0.f, Q = 0.f;
#pragma unroll
        for (int w = 0; w < TPB / 64; w++) { S += ls[w]; Q += lq[w]; }
        stats[blockIdx.x] = S;
        stats[nblocks + blockIdx.x] = Q;
    }
}

// Kernel 2: finalize mean and 1/std (unbiased, ddof=1) from block partials
__global__ void stats_kernel(const float* __restrict__ stats,
                             float* __restrict__ ms, int M, int nblocks)
{
    int tid = threadIdx.x;  // 64 threads
    float s = 0.f, q = 0.f;
    for (int b = tid; b < nblocks; b += 64) {
        s += stats[b];
        q += stats[nblocks + b];
    }
#pragma unroll
    for (int off = 32; off > 0; off >>= 1) {
        s += __shfl_xor(s, off, 64);
        q += __shfl_xor(q, off, 64);
    }
    if (tid == 0) {
        float mean = s / (float)M;
        float var = (q - s * s / (float)M) / (float)(M - 1);
        ms[0] = mean;
        ms[1] = 1.0f / sqrtf(var);
    }
}

// Kernel 3: standardize, compute row sq-norm, pack W2. packed[i] = {x0, x1, sq, w}
__global__ __launch_bounds__(TPB) void standardize_kernel(
    float4* __restrict__ packed, const float* __restrict__ W2,
    const float* __restrict__ ms)
{
    int i = blockIdx.x * TPB + threadIdx.x;
    float mean = ms[0], inv = ms[1];
    float4 p = packed[i];
    float x0 = (p.x - mean) * inv;
    float x1 = (p.y - mean) * inv;
    packed[i] = make_float4(x0, x1, fmaf(x0, x0, x1 * x1), W2[i]);
}

// Atomic-path init: out[i] = b2
__global__ void init_kernel(float* __restrict__ out, const float* __restrict__ b2v)
{
    out[blockIdx.x * TPB + threadIdx.x] = b2v[0];
}

// Kernel 4: the N^2 pair loop. Each thread owns RB rows; block stages a j-tile
// in LDS (broadcast reads, conflict-free). Deterministic partials per j-slice.
__global__ __launch_bounds__(TPB) void pair_kernel(
    const float4* __restrict__ packed, float* __restrict__ partial,
    float* __restrict__ out, int N, int JC, int useAtomic)
{
    __shared__ float4 tile[256];
    int tid = threadIdx.x;
    int rowBase = blockIdx.x * (TPB * RB);

    float2 xi[RB];
    float si[RB];
    float acc[RB];
#pragma unroll
    for (int r = 0; r < RB; r++) {
        float4 p = packed[rowBase + r * TPB + tid];
        xi[r] = make_float2(p.x, p.y);
        si[r] = p.z;
        acc[r] = 0.f;
    }

    int jbase = blockIdx.y * JC;
    for (int t = tid; t < JC; t += TPB) tile[t] = packed[jbase + t];
    __syncthreads();

#pragma unroll 2
    for (int jj = 0; jj < JC; jj++) {
        float4 p = tile[jj];
        float wq = -0.5f * p.w;
#pragma unroll
        for (int r = 0; r < RB; r++) {
            float d  = fmaf(xi[r].x, p.x, xi[r].y * p.y);
            float K  = fmaf(-2.f, d, si[r] + p.z);
            float t_ = fmaxf(K, 0.f);
            acc[r] = fmaf(wq * t_, __expf(t_), acc[r]);
        }
    }

    if (useAtomic) {
#pragma unroll
        for (int r = 0; r < RB; r++)
            atomicAdd(&out[rowBase + r * TPB + tid], acc[r]);
    } else {
#pragma unroll
        for (int r = 0; r < RB; r++)
            partial[(size_t)blockIdx.y * N + rowBase + r * TPB + tid] = acc[r];
    }
}

// Kernel 5: reduce j-slice partials, add b2
__global__ __launch_bounds__(TPB) void reduce_kernel(
    const float* __restrict__ partial, const float* __restrict__ b2v,
    float* __restrict__ out, int N, int JS)
{
    int i = blockIdx.x * TPB + threadIdx.x;
    float s = b2v[0];
    for (int b = 0; b < JS; b++) s += partial[(size_t)b * N + i];
    out[i] = s;
}

extern "C" void kernel_launch(void* const* d_in, const int* in_sizes, int n_in,
                              void* d_out, int out_size, void* d_ws, size_t ws_size,
                              hipStream_t stream)
{
    const float* XX = (const float*)d_in[0];
    const float* W1 = (const float*)d_in[1];
    const float* b1 = (const float*)d_in[2];
    const float* W2 = (const float*)d_in[3];
    const float* b2 = (const float*)d_in[4];
    float* out = (float*)d_out;

    int N = in_sizes[3];          // 8192 (W2 has N elements)
    int nblocksA = N / TPB;       // 32

    char* ws = (char*)d_ws;
    float4* packed = (float4*)ws;                       // N * 16 bytes
    float* stats = (float*)(ws + (size_t)N * 16);       // 2*nblocksA floats
    float* ms = stats + 2 * nblocksA;                   // mean, inv_std
    size_t partial_off = (size_t)N * 16 + (((size_t)(2 * nblocksA + 2) * 4 + 511) / 512) * 512;
    float* partial = (float*)(ws + partial_off);

    int JSPLIT = 64;
    int JC = N / JSPLIT;          // 128
    size_t need = partial_off + (size_t)JSPLIT * N * 4;
    int useAtomic = (ws_size < need) ? 1 : 0;

    trial_kernel<<<nblocksA, TPB, 0, stream>>>((const float2*)XX, W1, b1, packed, stats, nblocksA);
    stats_kernel<<<1, 64, 0, stream>>>(stats, ms, 2 * N, nblocksA);
    standardize_kernel<<<nblocksA, TPB, 0, stream>>>(packed, W2, ms);

    if (useAtomic) init_kernel<<<N / TPB, TPB, 0, stream>>>(out, b2);

    dim3 grid(N / (TPB * RB), JSPLIT);
    pair_kernel<<<grid, TPB, 0, stream>>>(packed, partial, out, N, JC, useAtomic);

    if (!useAtomic)
        reduce_kernel<<<N / TPB, TPB, 0, stream>>>(partial, b2, out, N, JSPLIT);
}

// Round 2
// 34.230 us; speedup vs baseline: 1.5525x; 1.5525x over previous
//
#include <hip/hip_runtime.h>

// Problem: N=8192 rows, D_IN=2. Pipeline:
//   y = XX@W1^T + b1 (8192x2); standardize over all 16384 elems (ddof=1);
//   K_ij = max(||x_i-x_j||^2, 0); out_i = sum_j (-0.5*K*exp(K))*W2_j + b2.
// Key algebra: x=(y-m)/s => ||x_i-x_j||^2 = (1/s^2)*||y_i-y_j||^2  (mean cancels).
// exp2 domain: with c = log2e/s^2, K_c = c*(r_i + r_j - 2 y_i.y_j) = log2e*K,
//   term = (-0.5*ln2*W2_j) * K_c * exp2(K_c).
// Per pair: 3 fma + fmax + mul + fma + v_exp_f32 = 6 VALU + 1 trans.

#define TPB2   256
#define JSPLIT 16    // j-slices (grid.y); partial[JSPLIT][N] then reduced
#define RPB    128   // rows per block = 16 rowthreads * RB
#define RB     8     // rows per thread
#define JPB    512   // j per block = N/JSPLIT (N=8192)
#define JPT    32    // j per thread = JPB/16 jslots

__device__ __forceinline__ void trial_y(float xx, float xy,
    float w00, float w01, float w10, float w11, float b0, float b1v,
    float& y0, float& y1)
{
    // identical fmaf sequence everywhere -> bit-identical y on row & col sides
    y0 = fmaf(xy, w01, fmaf(xx, w00, b0));
    y1 = fmaf(xy, w11, fmaf(xx, w10, b1v));
}

// K1: global stats of y over all 2N elements -> ms[0] = c = log2e / var (ddof=1)
__global__ __launch_bounds__(1024) void stats_kernel(
    const float4* __restrict__ XX4, const float* __restrict__ W1,
    const float* __restrict__ b1, float* __restrict__ ms, int N)
{
    int tid = threadIdx.x;
    float w00 = W1[0], w01 = W1[1], w10 = W1[2], w11 = W1[3];
    float b0 = b1[0], bb1 = b1[1];
    float s = 0.f, q = 0.f;
    int n4 = N >> 1;                      // two rows per float4
    for (int i = tid; i < n4; i += 1024) {
        float4 v = XX4[i];
        float y0, y1, y2, y3;
        trial_y(v.x, v.y, w00, w01, w10, w11, b0, bb1, y0, y1);
        trial_y(v.z, v.w, w00, w01, w10, w11, b0, bb1, y2, y3);
        s += (y0 + y1) + (y2 + y3);
        q += fmaf(y0, y0, y1 * y1) + fmaf(y2, y2, y3 * y3);
    }
#pragma unroll
    for (int o = 32; o > 0; o >>= 1) {
        s += __shfl_xor(s, o, 64);
        q += __shfl_xor(q, o, 64);
    }
    __shared__ float ls[16], lq[16];
    int w = tid >> 6;
    if ((tid & 63) == 0) { ls[w] = s; lq[w] = q; }
    __syncthreads();
    if (tid == 0) {
        float S = 0.f, Q = 0.f;
#pragma unroll
        for (int i = 0; i < 16; i++) { S += ls[i]; Q += lq[i]; }
        float M = (float)(2 * N);
        float var = (Q - S * S / M) / (M - 1.0f);   // unbiased, ddof=1
        ms[0] = 1.4426950408889634f / var;          // c = log2e * inv_var
    }
}

// K2: pair kernel. tid = jslot*16 + rt. Each thread: RB=8 rows, JPT=32 js.
// LDS tile padded 16B per 64 js -> jslot groups land on distinct bank quads
// (2-way broadcast-aliasing only, which is free on CDNA4).
__global__ __launch_bounds__(TPB2, 4) void pair_kernel(
    const float2* __restrict__ XX, const float* __restrict__ W1,
    const float* __restrict__ b1, const float* __restrict__ W2,
    const float* __restrict__ ms, float* __restrict__ partial, int N)
{
    __shared__ float4 tile[JPB + JPB / 64];   // +pad every 64 entries
    __shared__ float wred[4 * RPB];           // per-wave partial sums

    int tid = threadIdx.x;
    int jslot = tid >> 4, rt = tid & 15;

    float w00 = W1[0], w01 = W1[1], w10 = W1[2], w11 = W1[3];
    float b0 = b1[0], bb1 = b1[1];
    float c = ms[0];

    // stage j-tile: {y0, y1, r, -0.5*ln2*W2}
    int jbase = blockIdx.y * JPB;
    for (int i = tid; i < JPB; i += TPB2) {
        int j = jbase + i;
        float2 x = XX[j];
        float y0, y1;
        trial_y(x.x, x.y, w00, w01, w10, w11, b0, bb1, y0, y1);
        float r = fmaf(y0, y0, y1 * y1);
        float wj = -0.34657359027997264f * W2[j];   // -(ln2)/2 * W2
        tile[i + (i >> 6)] = make_float4(y0, y1, r, wj);
    }

    // row registers: A0 = -2c*y0, A1 = -2c*y1, B = c*r
    int rowBase = blockIdx.x * RPB;
    float A0[RB], A1[RB], B[RB], acc[RB];
    float m2c = -2.0f * c;
#pragma unroll
    for (int r = 0; r < RB; r++) {
        int row = rowBase + r * 16 + rt;
        float2 x = XX[row];
        float y0, y1;
        trial_y(x.x, x.y, w00, w01, w10, w11, b0, bb1, y0, y1);
        A0[r] = m2c * y0;
        A1[r] = m2c * y1;
        B[r]  = c * fmaf(y0, y0, y1 * y1);
        acc[r] = 0.f;
    }
    __syncthreads();

    const float4* tbase = tile + jslot * JPT + (jslot >> 1);
#pragma unroll 2
    for (int k = 0; k < JPT; k++) {
        float4 qj = tbase[k];
#pragma unroll
        for (int r = 0; r < RB; r++) {
            float kc = fmaf(A0[r], qj.x, fmaf(A1[r], qj.y, fmaf(c, qj.z, B[r])));
            float t  = fmaxf(kc, 0.f);
            float e  = exp2f(t);                    // v_exp_f32
            acc[r]   = fmaf(qj.w * t, e, acc[r]);
        }
    }

    // reduce over 16 jslots: lanes l, l^16, l^32 are jslot^1, jslot^2 (same rt)
#pragma unroll
    for (int r = 0; r < RB; r++) {
        acc[r] += __shfl_xor(acc[r], 16, 64);
        acc[r] += __shfl_xor(acc[r], 32, 64);
    }
    int w = tid >> 6, l = tid & 63;
    if (l < 16) {
#pragma unroll
        for (int r = 0; r < RB; r++)
            wred[w * RPB + l * RB + r] = acc[r];
    }
    __syncthreads();
    if (tid < RPB) {
        // row_local = tid = r*16 + rt  ->  r = tid>>4, rt = tid&15
        int rt2 = tid & 15, r2 = tid >> 4;
        float s = 0.f;
#pragma unroll
        for (int w2 = 0; w2 < 4; w2++)
            s += wred[w2 * RPB + rt2 * RB + r2];
        partial[(size_t)blockIdx.y * N + rowBase + tid] = s;
    }
}

// K3: out[i] = b2 + sum over JSPLIT slices (fixed order, deterministic)
__global__ __launch_bounds__(256) void reduce_kernel(
    const float* __restrict__ partial, const float* __restrict__ b2,
    float* __restrict__ out, int N)
{
    int i = blockIdx.x * 256 + threadIdx.x;
    float s = b2[0];
#pragma unroll
    for (int k = 0; k < JSPLIT; k++)
        s += partial[(size_t)k * N + i];
    out[i] = s;
}

extern "C" void kernel_launch(void* const* d_in, const int* in_sizes, int n_in,
                              void* d_out, int out_size, void* d_ws, size_t ws_size,
                              hipStream_t stream)
{
    const float* XX = (const float*)d_in[0];
    const float* W1 = (const float*)d_in[1];
    const float* b1 = (const float*)d_in[2];
    const float* W2 = (const float*)d_in[3];
    const float* b2 = (const float*)d_in[4];
    float* out = (float*)d_out;

    int N = in_sizes[3];   // 8192

    char* ws = (char*)d_ws;
    float* ms = (float*)ws;                      // [0] = c
    float* partial = (float*)(ws + 256);         // JSPLIT * N floats

    stats_kernel<<<1, 1024, 0, stream>>>((const float4*)XX, W1, b1, ms, N);

    dim3 grid(N / RPB, JSPLIT);                  // (64, 16) -> 1024 blocks, 4/CU
    pair_kernel<<<grid, TPB2, 0, stream>>>((const float2*)XX, W1, b1, W2, ms,
                                           partial, N);

    reduce_kernel<<<N / 256, 256, 0, stream>>>(partial, b2, out, N);
}

// Round 3
// 30.108 us; speedup vs baseline: 1.7650x; 1.1369x over previous
//
#include <hip/hip_runtime.h>

// Fully fused: stats + trial layer + N^2 RBF-ish reduction in ONE kernel.
//   y = XX@W1^T + b1; standardize over all 2N elems (ddof=1) => only need
//   c = log2e/var (mean cancels in pairwise differences).
//   kc = c*(r_i + r_j - 2 y_i.y_j) = log2e*K;  term = (-ln2/2*W2_j)*kc*2^kc.
// Every block recomputes stats identically (fixed-order) -> deterministic.
// Per pair: 3 fma + mul + fma + v_exp_f32 (fmax dropped: K>=0 up to ~1e-7,
// error ~1e-11 vs threshold 1.2e3).

#define NBLK 512
#define TPB  512
#define NRT  16            // row-threads (share tile reads via broadcast)
#define NJS  32            // j-slots
#define RPB  16            // rows per block = 8192/NBLK
#define TJ   1024          // j-tile width
#define NT   8             // tiles = N/TJ
#define KPT  (TJ / NJS)    // 32 j per thread per tile
#define PADI(i) ((i) + ((i) >> 5))   // pad 1 float4 per 32 -> conflict-free jslot reads
#define TSZ  (TJ + TJ / 32)

__global__ __launch_bounds__(TPB) void fused_kernel(
    const float2* __restrict__ XX, const float* __restrict__ W1,
    const float* __restrict__ b1, const float* __restrict__ W2,
    const float* __restrict__ b2, float* __restrict__ out, int N)
{
    __shared__ float4 tile[2][TSZ];
    __shared__ float ls[8], lq[8];
    __shared__ float csh;
    __shared__ float wred[8 * NRT];

    int tid = threadIdx.x;
    float w00 = W1[0], w01 = W1[1], w10 = W1[2], w11 = W1[3];
    float b0 = b1[0], bb1 = b1[1];

    // --- stats partial (identical order in every block -> identical c) ---
    const float4* XX4 = (const float4*)XX;
    float s = 0.f, q = 0.f;
    int n4 = N >> 1;
    for (int i = tid; i < n4; i += TPB) {
        float4 v = XX4[i];
        float y0 = fmaf(v.y, w01, fmaf(v.x, w00, b0));
        float y1 = fmaf(v.y, w11, fmaf(v.x, w10, bb1));
        float y2 = fmaf(v.w, w01, fmaf(v.z, w00, b0));
        float y3 = fmaf(v.w, w11, fmaf(v.z, w10, bb1));
        s += (y0 + y1) + (y2 + y3);
        q += fmaf(y0, y0, y1 * y1) + fmaf(y2, y2, y3 * y3);
    }

    // --- stage tile 0 (c-free: {y0, y1, r, -ln2/2*W2}) overlaps stats ---
    for (int i = tid; i < TJ; i += TPB) {
        float2 x = XX[i];
        float y0 = fmaf(x.y, w01, fmaf(x.x, w00, b0));
        float y1 = fmaf(x.y, w11, fmaf(x.x, w10, bb1));
        float r = fmaf(y0, y0, y1 * y1);
        tile[0][PADI(i)] = make_float4(y0, y1, r, -0.34657359027997264f * W2[i]);
    }

    // --- stats reduce ---
#pragma unroll
    for (int o = 32; o > 0; o >>= 1) {
        s += __shfl_xor(s, o, 64);
        q += __shfl_xor(q, o, 64);
    }
    int w = tid >> 6;
    if ((tid & 63) == 0) { ls[w] = s; lq[w] = q; }
    __syncthreads();
    if (tid == 0) {
        float S = 0.f, Q = 0.f;
#pragma unroll
        for (int i = 0; i < 8; i++) { S += ls[i]; Q += lq[i]; }
        float M = (float)(2 * N);
        float var = (Q - S * S / M) / (M - 1.0f);   // ddof=1
        csh = 1.4426950408889634f / var;            // c = log2e / var
    }
    __syncthreads();
    float c = csh;

    // --- row registers ---
    int rt = tid & (NRT - 1), jslot = tid >> 4;
    int row = blockIdx.x * RPB + rt;
    float2 xr = XX[row];
    float ry0 = fmaf(xr.y, w01, fmaf(xr.x, w00, b0));
    float ry1 = fmaf(xr.y, w11, fmaf(xr.x, w10, bb1));
    float A0 = -2.0f * c * ry0;
    float A1 = -2.0f * c * ry1;
    float B  = c * fmaf(ry0, ry0, ry1 * ry1);
    float acc = 0.f;

    // --- main loop: double-buffered tiles, 1 barrier per tile ---
    int buf = 0;
    for (int t = 0; t < NT; t++) {
        if (t + 1 < NT) {
            int jb = (t + 1) * TJ;
            for (int i = tid; i < TJ; i += TPB) {
                int j = jb + i;
                float2 x = XX[j];
                float y0 = fmaf(x.y, w01, fmaf(x.x, w00, b0));
                float y1 = fmaf(x.y, w11, fmaf(x.x, w10, bb1));
                float r = fmaf(y0, y0, y1 * y1);
                tile[buf ^ 1][PADI(i)] = make_float4(y0, y1, r, -0.34657359027997264f * W2[j]);
            }
        }
        const float4* tb = &tile[buf][jslot * KPT + jslot];  // PADI(jslot*32+k) = jslot*33+k
#pragma unroll 8
        for (int k = 0; k < KPT; k++) {
            float4 qj = tb[k];
            float kc = fmaf(A1, qj.y, fmaf(A0, qj.x, fmaf(c, qj.z, B)));
            float e  = exp2f(kc);                    // v_exp_f32
            acc = fmaf(qj.w * kc, e, acc);
        }
        __syncthreads();
        buf ^= 1;
    }

    // --- reduce 32 jslots: shfl within wave (4 jslots), then LDS across 8 waves ---
    acc += __shfl_xor(acc, 16, 64);
    acc += __shfl_xor(acc, 32, 64);
    int lane = tid & 63;
    if (lane < NRT) wred[w * NRT + lane] = acc;
    __syncthreads();
    if (tid < RPB) {
        float r = b2[0];
#pragma unroll
        for (int ww = 0; ww < 8; ww++) r += wred[ww * NRT + tid];
        out[blockIdx.x * RPB + tid] = r;
    }
}

extern "C" void kernel_launch(void* const* d_in, const int* in_sizes, int n_in,
                              void* d_out, int out_size, void* d_ws, size_t ws_size,
                              hipStream_t stream)
{
    const float* XX = (const float*)d_in[0];
    const float* W1 = (const float*)d_in[1];
    const float* b1 = (const float*)d_in[2];
    const float* W2 = (const float*)d_in[3];
    const float* b2 = (const float*)d_in[4];
    float* out = (float*)d_out;

    int N = in_sizes[3];   // 8192

    fused_kernel<<<NBLK, TPB, 0, stream>>>((const float2*)XX, W1, b1, W2, b2, out, N);
}

// Round 4
// 28.853 us; speedup vs baseline: 1.8418x; 1.0435x over previous
//
#include <hip/hip_runtime.h>

// Fully fused single kernel, register-blocked RB=8 rows/thread.
//   y = XX@W1^T + b1; standardize over all 2N elems (ddof=1) => only
//   c = log2e/var needed (mean cancels in pairwise differences).
//   kc = c*(r_i + r_j - 2 y_i.y_j) = log2e*K;  term = (-ln2/2*W2_j)*kc*2^kc.
// Per pair: 3 fma + mul + fma + v_exp_f32. One LDS float4 serves RB=8 pairs
// (2 B/pair -> LDS ~2us, vs 15.5us at RB=1 which bound round 2).
// Every block recomputes stats in identical fixed order -> deterministic.

#define NBLK 512
#define TPB  512
#define NRT  2               // row-threads per jslot group
#define NJS  256             // j-slots  (NRT*NJS = TPB)
#define RB   8               // rows per thread
#define RPB  (NRT * RB)      // 16 rows per block
#define TJ   1024            // j-tile width
#define NT   8               // tiles = N/TJ
#define KPT  (TJ / NJS)      // 4 float4 reads per thread per tile

__global__ __launch_bounds__(TPB) void fused_kernel(
    const float2* __restrict__ XX, const float* __restrict__ W1,
    const float* __restrict__ b1, const float* __restrict__ W2,
    const float* __restrict__ b2, float* __restrict__ out, int N)
{
    __shared__ float4 tile[2][TJ];
    __shared__ float ls[8], lq[8];
    __shared__ float csh;
    __shared__ float wred[8][RPB];

    int tid = threadIdx.x;
    float w00 = W1[0], w01 = W1[1], w10 = W1[2], w11 = W1[3];
    float b0 = b1[0], bb1 = b1[1];

    // --- stats partial (identical order in every block -> identical c) ---
    const float4* XX4 = (const float4*)XX;
    float s = 0.f, q = 0.f;
    int n4 = N >> 1;                         // 4096 float4s, 8 iters
    for (int i = tid; i < n4; i += TPB) {
        float4 v = XX4[i];
        float y0 = fmaf(v.y, w01, fmaf(v.x, w00, b0));
        float y1 = fmaf(v.y, w11, fmaf(v.x, w10, bb1));
        float y2 = fmaf(v.w, w01, fmaf(v.z, w00, b0));
        float y3 = fmaf(v.w, w11, fmaf(v.z, w10, bb1));
        s += (y0 + y1) + (y2 + y3);
        q += fmaf(y0, y0, y1 * y1) + fmaf(y2, y2, y3 * y3);
    }

    // --- stage tile 0 (c-free entries: {y0, y1, r, -ln2/2*W2}) ---
#pragma unroll
    for (int ii = 0; ii < TJ / TPB; ii++) {
        int i = ii * TPB + tid;
        float2 x = XX[i];
        float y0 = fmaf(x.y, w01, fmaf(x.x, w00, b0));
        float y1 = fmaf(x.y, w11, fmaf(x.x, w10, bb1));
        float r = fmaf(y0, y0, y1 * y1);
        tile[0][i] = make_float4(y0, y1, r, -0.34657359027997264f * W2[i]);
    }

    // --- stats reduce ---
#pragma unroll
    for (int o = 32; o > 0; o >>= 1) {
        s += __shfl_xor(s, o, 64);
        q += __shfl_xor(q, o, 64);
    }
    int w = tid >> 6;
    if ((tid & 63) == 0) { ls[w] = s; lq[w] = q; }
    __syncthreads();
    if (tid == 0) {
        float S = 0.f, Q = 0.f;
#pragma unroll
        for (int i = 0; i < 8; i++) { S += ls[i]; Q += lq[i]; }
        float M = (float)(2 * N);
        float var = (Q - S * S / M) / (M - 1.0f);   // ddof=1
        csh = 1.4426950408889634f / var;            // c = log2e / var
    }
    __syncthreads();
    float c = csh;

    // --- row registers: RB=8 rows per thread ---
    int rt = tid & (NRT - 1), jslot = tid >> 1;  // NRT == 2
    int rowBase = blockIdx.x * RPB + rt * RB;
    float A0[RB], A1[RB], B[RB], acc[RB];
    float m2c = -2.0f * c;
#pragma unroll
    for (int r = 0; r < RB; r++) {
        float2 x = XX[rowBase + r];
        float y0 = fmaf(x.y, w01, fmaf(x.x, w00, b0));
        float y1 = fmaf(x.y, w11, fmaf(x.x, w10, bb1));
        A0[r] = m2c * y0;
        A1[r] = m2c * y1;
        B[r]  = c * fmaf(y0, y0, y1 * y1);
        acc[r] = 0.f;
    }

    // --- main loop: double-buffered tiles, 1 barrier per tile ---
    int buf = 0;
    for (int t = 0; t < NT; t++) {
        if (t + 1 < NT) {
            int jb = (t + 1) * TJ;
#pragma unroll
            for (int ii = 0; ii < TJ / TPB; ii++) {
                int i = ii * TPB + tid;
                float2 x = XX[jb + i];
                float y0 = fmaf(x.y, w01, fmaf(x.x, w00, b0));
                float y1 = fmaf(x.y, w11, fmaf(x.x, w10, bb1));
                float r = fmaf(y0, y0, y1 * y1);
                tile[buf ^ 1][i] = make_float4(y0, y1, r, -0.34657359027997264f * W2[jb + i]);
            }
        }
        const float4* tb = tile[buf];
#pragma unroll
        for (int k = 0; k < KPT; k++) {
            float4 qj = tb[k * NJS + jslot];   // 32 consecutive f4/wave, 2-way bcast
#pragma unroll
            for (int r = 0; r < RB; r++) {
                float kc = fmaf(A0[r], qj.x, fmaf(A1[r], qj.y, fmaf(c, qj.z, B[r])));
                float e  = exp2f(kc);          // v_exp_f32
                acc[r]   = fmaf(qj.w * kc, e, acc[r]);
            }
        }
        __syncthreads();
        buf ^= 1;
    }

    // --- reduce across 256 jslots ---
    // same-rt lanes are xor-strides {2,4,8,16,32}: wave-level jslot sum
#pragma unroll
    for (int r = 0; r < RB; r++) {
        acc[r] += __shfl_xor(acc[r], 2, 64);
        acc[r] += __shfl_xor(acc[r], 4, 64);
        acc[r] += __shfl_xor(acc[r], 8, 64);
        acc[r] += __shfl_xor(acc[r], 16, 64);
        acc[r] += __shfl_xor(acc[r], 32, 64);
    }
    int lane = tid & 63;
    if (lane < NRT) {
#pragma unroll
        for (int r = 0; r < RB; r++)
            wred[w][lane * RB + r] = acc[r];
    }
    __syncthreads();
    if (tid < RPB) {
        float sR = b2[0];
#pragma unroll
        for (int ww = 0; ww < 8; ww++) sR += wred[ww][tid];
        out[blockIdx.x * RPB + tid] = sR;
    }
}

extern "C" void kernel_launch(void* const* d_in, const int* in_sizes, int n_in,
                              void* d_out, int out_size, void* d_ws, size_t ws_size,
                              hipStream_t stream)
{
    const float* XX = (const float*)d_in[0];
    const float* W1 = (const float*)d_in[1];
    const float* b1 = (const float*)d_in[2];
    const float* W2 = (const float*)d_in[3];
    const float* b2 = (const float*)d_in[4];
    float* out = (float*)d_out;

    int N = in_sizes[3];   // 8192

    fused_kernel<<<N / RPB, TPB, 0, stream>>>((const float2*)XX, W1, b1, W2, b2, out, N);
}

// Round 5
// 20.956 us; speedup vs baseline: 2.5358x; 1.3768x over previous
//
#include <hip/hip_runtime.h>

// Fully fused single kernel, register-blocked RB=8 rows/thread, packed-fp32.
//   y = XX@W1^T + b1; standardize over all 2N elems (ddof=1) => only
//   c = log2e/var needed (mean cancels in pairwise differences).
//   kc = c*(r_i + r_j - 2 y_i.y_j) = log2e*K;  term = (-ln2/2*W2_j)*kc*2^kc.
// Inner loop: v_pk_fma_f32 (2 rows per instruction) + raw v_exp_f32.
// Every block recomputes stats in identical fixed order -> deterministic.

#define NN   8192
#define TPB  512
#define NRT  2               // row-threads per jslot group
#define NJS  256             // j-slots  (NRT*NJS = TPB)
#define RB   8               // rows per thread (4 v2f pairs)
#define RPB  (NRT * RB)      // 16 rows per block
#define TJ   1024            // j-tile width
#define NT   (NN / TJ)       // 8
#define KPT  (TJ / NJS)      // 4 float4 reads per thread per tile

typedef float v2f __attribute__((ext_vector_type(2)));

#if __has_builtin(__builtin_amdgcn_exp2f)
#define EXP2(x) __builtin_amdgcn_exp2f(x)
#else
#define EXP2(x) exp2f(x)
#endif

__global__ __launch_bounds__(TPB) void fused_kernel(
    const float2* __restrict__ XX, const float* __restrict__ W1,
    const float* __restrict__ b1, const float* __restrict__ W2,
    const float* __restrict__ b2, float* __restrict__ out)
{
    __shared__ float4 tile[2][TJ];
    __shared__ float ls[8], lq[8];
    __shared__ float csh;
    __shared__ float wred[8][RPB];

    int tid = threadIdx.x;
    float w00 = W1[0], w01 = W1[1], w10 = W1[2], w11 = W1[3];
    float b0 = b1[0], bb1 = b1[1];

    // --- stats partial (identical order in every block -> identical c) ---
    const float4* XX4 = (const float4*)XX;
    float s = 0.f, q = 0.f;
#pragma unroll
    for (int ii = 0; ii < (NN / 2) / TPB; ii++) {      // 8 unrolled iters
        float4 v = XX4[ii * TPB + tid];
        float y0 = fmaf(v.y, w01, fmaf(v.x, w00, b0));
        float y1 = fmaf(v.y, w11, fmaf(v.x, w10, bb1));
        float y2 = fmaf(v.w, w01, fmaf(v.z, w00, b0));
        float y3 = fmaf(v.w, w11, fmaf(v.z, w10, bb1));
        s += (y0 + y1) + (y2 + y3);
        q += fmaf(y0, y0, y1 * y1) + fmaf(y2, y2, y3 * y3);
    }

    // --- stage tile 0 (c-free entries: {y0, y1, r, -ln2/2*W2}) ---
#pragma unroll
    for (int ii = 0; ii < TJ / TPB; ii++) {
        int i = ii * TPB + tid;
        float2 x = XX[i];
        float y0 = fmaf(x.y, w01, fmaf(x.x, w00, b0));
        float y1 = fmaf(x.y, w11, fmaf(x.x, w10, bb1));
        float r = fmaf(y0, y0, y1 * y1);
        tile[0][i] = make_float4(y0, y1, r, -0.34657359027997264f * W2[i]);
    }

    // --- stats reduce ---
#pragma unroll
    for (int o = 32; o > 0; o >>= 1) {
        s += __shfl_xor(s, o, 64);
        q += __shfl_xor(q, o, 64);
    }
    int w = tid >> 6;
    if ((tid & 63) == 0) { ls[w] = s; lq[w] = q; }
    __syncthreads();
    if (tid == 0) {
        float S = 0.f, Q = 0.f;
#pragma unroll
        for (int i = 0; i < 8; i++) { S += ls[i]; Q += lq[i]; }
        float M = (float)(2 * NN);
        float var = (Q - S * S / M) / (M - 1.0f);   // ddof=1
        csh = 1.4426950408889634f / var;            // c = log2e / var
    }
    __syncthreads();
    float c = csh;

    // --- row registers: RB=8 rows per thread, packed into 4 v2f pairs ---
    int rt = tid & (NRT - 1), jslot = tid >> 1;     // NRT == 2
    int rowBase = blockIdx.x * RPB + rt * RB;
    v2f A0p[4], A1p[4], Bp[4], accp[4];
    const v2f cp = {c, c};
    float m2c = -2.0f * c;
#pragma unroll
    for (int h = 0; h < 4; h++) {
        float2 xa = XX[rowBase + 2 * h];
        float2 xb = XX[rowBase + 2 * h + 1];
        float ya0 = fmaf(xa.y, w01, fmaf(xa.x, w00, b0));
        float ya1 = fmaf(xa.y, w11, fmaf(xa.x, w10, bb1));
        float yb0 = fmaf(xb.y, w01, fmaf(xb.x, w00, b0));
        float yb1 = fmaf(xb.y, w11, fmaf(xb.x, w10, bb1));
        A0p[h] = (v2f){m2c * ya0, m2c * yb0};
        A1p[h] = (v2f){m2c * ya1, m2c * yb1};
        Bp[h]  = (v2f){c * fmaf(ya0, ya0, ya1 * ya1), c * fmaf(yb0, yb0, yb1 * yb1)};
        accp[h] = (v2f){0.f, 0.f};
    }

    // --- main loop: double-buffered tiles, 1 barrier per tile ---
    int buf = 0;
    for (int t = 0; t < NT; t++) {
        if (t + 1 < NT) {
            int jb = (t + 1) * TJ;
#pragma unroll
            for (int ii = 0; ii < TJ / TPB; ii++) {
                int i = ii * TPB + tid;
                float2 x = XX[jb + i];
                float y0 = fmaf(x.y, w01, fmaf(x.x, w00, b0));
                float y1 = fmaf(x.y, w11, fmaf(x.x, w10, bb1));
                float r = fmaf(y0, y0, y1 * y1);
                tile[buf ^ 1][i] = make_float4(y0, y1, r, -0.34657359027997264f * W2[jb + i]);
            }
        }
        const float4* tb = tile[buf];
#pragma unroll
        for (int k = 0; k < KPT; k++) {
            float4 qj = tb[k * NJS + jslot];   // 32 consecutive f4/wave, 2-way bcast
            v2f qx = {qj.x, qj.x};
            v2f qy = {qj.y, qj.y};
            v2f qz = {qj.z, qj.z};
            v2f qw = {qj.w, qj.w};
#pragma unroll
            for (int h = 0; h < 4; h++) {
                v2f kc = __builtin_elementwise_fma(A0p[h], qx,
                         __builtin_elementwise_fma(A1p[h], qy,
                         __builtin_elementwise_fma(cp, qz, Bp[h])));
                v2f e;
                e.x = EXP2(kc.x);               // v_exp_f32
                e.y = EXP2(kc.y);
                accp[h] = __builtin_elementwise_fma(qw * kc, e, accp[h]);
            }
        }
        __syncthreads();
        buf ^= 1;
    }

    // --- reduce across 256 jslots: wave-level xor-shfl, then LDS across waves ---
#pragma unroll
    for (int h = 0; h < 4; h++) {
#pragma unroll
        for (int o = 2; o <= 32; o <<= 1) {
            accp[h].x += __shfl_xor(accp[h].x, o, 64);
            accp[h].y += __shfl_xor(accp[h].y, o, 64);
        }
    }
    int lane = tid & 63;
    if (lane < NRT) {
#pragma unroll
        for (int h = 0; h < 4; h++) {
            wred[w][lane * RB + 2 * h]     = accp[h].x;
            wred[w][lane * RB + 2 * h + 1] = accp[h].y;
        }
    }
    __syncthreads();
    if (tid < RPB) {
        float sR = b2[0];
#pragma unroll
        for (int ww = 0; ww < 8; ww++) sR += wred[ww][tid];
        out[blockIdx.x * RPB + tid] = sR;
    }
}

extern "C" void kernel_launch(void* const* d_in, const int* in_sizes, int n_in,
                              void* d_out, int out_size, void* d_ws, size_t ws_size,
                              hipStream_t stream)
{
    const float* XX = (const float*)d_in[0];
    const float* W1 = (const float*)d_in[1];
    const float* b1 = (const float*)d_in[2];
    const float* W2 = (const float*)d_in[3];
    const float* b2 = (const float*)d_in[4];
    float* out = (float*)d_out;

    fused_kernel<<<NN / RPB, TPB, 0, stream>>>((const float2*)XX, W1, b1, W2, b2, out);
}

// Round 6
// 20.284 us; speedup vs baseline: 2.6198x; 1.0331x over previous
//
#include <hip/hip_runtime.h>

// Fused single kernel, NO LDS tile: j-stream is L2-resident (96KB), so each
// thread reads XX[j]/W2[j] straight from global (coalesced) and recomputes
// y_j inline (amortized over RB=16 rows). Zero staging, 2 barriers total.
//   y = XX@W1^T + b1; standardize over all 2N elems (ddof=1) => only
//   c = log2e/var needed (mean cancels in pairwise differences).
//   kc = c*(r_i + r_j - 2 y_i.y_j) = log2e*K;  term = (-ln2/2*W2_j)*kc*2^kc.
// Inner per 2 pairs: 3 pk_fma + pk_mul + pk_fma + 2 v_exp_f32.
// Every block recomputes stats in identical fixed order -> deterministic.

#define NN   8192
#define TPB  512
#define RB   16              // rows per block (all threads share these rows)
#define NH   (RB / 2)        // 8 v2f row-groups
#define JPT  (NN / TPB)      // 16 j per thread

typedef float v2f __attribute__((ext_vector_type(2)));

#if __has_builtin(__builtin_amdgcn_exp2f)
#define EXP2(x) __builtin_amdgcn_exp2f(x)
#else
#define EXP2(x) exp2f(x)
#endif

__global__ __launch_bounds__(TPB) void fused_kernel(
    const float2* __restrict__ XX, const float* __restrict__ W1,
    const float* __restrict__ b1, const float* __restrict__ W2,
    const float* __restrict__ b2, float* __restrict__ out)
{
    __shared__ float ls[8], lq[8];
    __shared__ float csh;
    __shared__ float wred[8][RB];

    int tid = threadIdx.x;
    float w00 = W1[0], w01 = W1[1], w10 = W1[2], w11 = W1[3];
    float b0 = b1[0], bb1 = b1[1];

    // --- stats partial (identical order in every block -> identical c) ---
    const float4* XX4 = (const float4*)XX;
    float s = 0.f, q = 0.f;
#pragma unroll
    for (int ii = 0; ii < (NN / 2) / TPB; ii++) {      // 8 unrolled iters
        float4 v = XX4[ii * TPB + tid];
        float y0 = fmaf(v.y, w01, fmaf(v.x, w00, b0));
        float y1 = fmaf(v.y, w11, fmaf(v.x, w10, bb1));
        float y2 = fmaf(v.w, w01, fmaf(v.z, w00, b0));
        float y3 = fmaf(v.w, w11, fmaf(v.z, w10, bb1));
        s += (y0 + y1) + (y2 + y3);
        q += fmaf(y0, y0, y1 * y1) + fmaf(y2, y2, y3 * y3);
    }
#pragma unroll
    for (int o = 32; o > 0; o >>= 1) {
        s += __shfl_xor(s, o, 64);
        q += __shfl_xor(q, o, 64);
    }
    int wv = tid >> 6;
    if ((tid & 63) == 0) { ls[wv] = s; lq[wv] = q; }
    __syncthreads();
    if (tid == 0) {
        float S = 0.f, Q = 0.f;
#pragma unroll
        for (int i = 0; i < 8; i++) { S += ls[i]; Q += lq[i]; }
        float M = (float)(2 * NN);
        float var = (Q - S * S / M) / (M - 1.0f);   // ddof=1
        csh = 1.4426950408889634f / var;            // c = log2e / var
    }
    __syncthreads();
    float c = csh;

    // --- row registers: RB=16 rows per block, 8 v2f groups per thread ---
    int rowBase = blockIdx.x * RB;
    v2f A0p[NH], A1p[NH], Bp[NH], accp[NH];
    const v2f cp = {c, c};
    float m2c = -2.0f * c;
#pragma unroll
    for (int h = 0; h < NH; h++) {
        float2 xa = XX[rowBase + 2 * h];
        float2 xb = XX[rowBase + 2 * h + 1];
        float ya0 = fmaf(xa.y, w01, fmaf(xa.x, w00, b0));
        float ya1 = fmaf(xa.y, w11, fmaf(xa.x, w10, bb1));
        float yb0 = fmaf(xb.y, w01, fmaf(xb.x, w00, b0));
        float yb1 = fmaf(xb.y, w11, fmaf(xb.x, w10, bb1));
        A0p[h] = (v2f){m2c * ya0, m2c * yb0};
        A1p[h] = (v2f){m2c * ya1, m2c * yb1};
        Bp[h]  = (v2f){c * fmaf(ya0, ya0, ya1 * ya1), c * fmaf(yb0, yb0, yb1 * yb1)};
        accp[h] = (v2f){0.f, 0.f};
    }

    // --- main loop: j straight from global (L2-resident), no LDS, no barriers ---
#pragma unroll 4
    for (int k = 0; k < JPT; k++) {
        int j = k * TPB + tid;                 // lanes -> consecutive j: coalesced
        float2 xj = XX[j];
        float wj = W2[j];
        float y0 = fmaf(xj.y, w01, fmaf(xj.x, w00, b0));
        float y1 = fmaf(xj.y, w11, fmaf(xj.x, w10, bb1));
        float rj = fmaf(y0, y0, y1 * y1);
        float gw = -0.34657359027997264f * wj; // -(ln2)/2 * W2_j
        v2f qx = {y0, y0};
        v2f qy = {y1, y1};
        v2f qz = {rj, rj};
        v2f qw = {gw, gw};
#pragma unroll
        for (int h = 0; h < NH; h++) {
            v2f kc = __builtin_elementwise_fma(A0p[h], qx,
                     __builtin_elementwise_fma(A1p[h], qy,
                     __builtin_elementwise_fma(cp, qz, Bp[h])));
            v2f e;
            e.x = EXP2(kc.x);                  // v_exp_f32
            e.y = EXP2(kc.y);
            accp[h] = __builtin_elementwise_fma(qw * kc, e, accp[h]);
        }
    }

    // --- reduce: 512 threads all hold partials for the same 16 rows ---
#pragma unroll
    for (int h = 0; h < NH; h++) {
#pragma unroll
        for (int o = 1; o <= 32; o <<= 1) {
            accp[h].x += __shfl_xor(accp[h].x, o, 64);
            accp[h].y += __shfl_xor(accp[h].y, o, 64);
        }
    }
    if ((tid & 63) == 0) {
#pragma unroll
        for (int h = 0; h < NH; h++) {
            wred[wv][2 * h]     = accp[h].x;
            wred[wv][2 * h + 1] = accp[h].y;
        }
    }
    __syncthreads();
    if (tid < RB) {
        float sR = b2[0];
#pragma unroll
        for (int ww = 0; ww < 8; ww++) sR += wred[ww][tid];
        out[rowBase + tid] = sR;
    }
}

extern "C" void kernel_launch(void* const* d_in, const int* in_sizes, int n_in,
                              void* d_out, int out_size, void* d_ws, size_t ws_size,
                              hipStream_t stream)
{
    const float* XX = (const float*)d_in[0];
    const float* W1 = (const float*)d_in[1];
    const float* b1 = (const float*)d_in[2];
    const float* W2 = (const float*)d_in[3];
    const float* b2 = (const float*)d_in[4];
    float* out = (float*)d_out;

    fused_kernel<<<NN / RB, TPB, 0, stream>>>((const float2*)XX, W1, b1, W2, b2, out);
}